// Round 6
// baseline (975.266 us; speedup 1.0000x reference)
//
#include <hip/hip_runtime.h>

#define B_   16
#define D_   512
#define T_   2000
#define Q_   8
#define CD_  8
#define CS_  1024
#define NCOL 32000   // B_*T_

// workspace float offsets
#define WS_Z0   0              // 64*32000 = 2048000
#define WS_ZQ   2048000        // 64*32000 = 2048000
#define WS_M    4096000        // 64*64    = 4096
#define WS_VBP  4100096        // 8*8*8    = 512
#define WS_LP   4100608        // 8*1000   = 8000
#define WS_INV  4108608        // 8*1024   = 8192

// d_out float offsets (quantized_out, all_idx, all_loss, all_q)
#define OFF_QOUT 0
#define OFF_IDX  16384000
#define OFF_LOSS 16640000
#define OFF_ALLQ 16640008

// ---------------- K_pre: fused M + vbp + codebook inverse norms ----------------
// blocks 0..63: q=blk>>3,p=blk&7; threads 0..63 compute M, 64..127 compute vbp.
// blocks 64..95: inverse norms for 8192 codebook rows.
__global__ __launch_bounds__(256) void k_pre(const float* __restrict__ Wi,
                                             const float* __restrict__ Wo,
                                             const float* __restrict__ bo,
                                             const float* __restrict__ cb,
                                             float* __restrict__ ws) {
    int blk = blockIdx.x, tid = threadIdx.x;
    if (blk < 64) {
        int q = blk >> 3, p = blk & 7;
        if (tid < 64) {
            int c = tid >> 3, cp = tid & 7;
            const float* wir = Wi + (q * CD_ + c) * D_;
            const float* wop = Wo + p * (D_ * CD_) + cp;
            double acc = 0.0;
            #pragma unroll 4
            for (int d = 0; d < D_; ++d) acc += (double)wir[d] * (double)wop[d * CD_];
            ws[WS_M + (q * 8 + p) * 64 + c * 8 + cp] = (float)acc;
        } else if (tid < 128) {
            int s = tid - 64;
            int c = s >> 3, ds = s & 7;
            double a = 0.0;
            if (p < q) {
                const float* wir = Wi + (q * CD_ + c) * D_;
                const float* bop = bo + p * D_;
                for (int d = ds; d < D_; d += 8) a += (double)wir[d] * (double)bop[d];
            }
            a += __shfl_xor(a, 1);
            a += __shfl_xor(a, 2);
            a += __shfl_xor(a, 4);
            if (ds == 0) ws[WS_VBP + (q * 8 + p) * 8 + c] = (float)a;
        }
    } else {
        int id = (blk - 64) * 256 + tid;   // 0..8191
        const float4* r = (const float4*)(cb + (size_t)id * CD_);
        float4 v = r[0], w = r[1];
        float ss = v.x * v.x + v.y * v.y + v.z * v.z + v.w * v.w;
        float so = w.x * w.x + w.y * w.y + w.z * w.z + w.w * w.w;
        float nrm = sqrtf(ss + so);
        ws[WS_INV + id] = 1.0f / fmaxf(nrm, 1e-12f);
    }
}

// ---------------- K_z0: Z0[row][col], 8 rows/thread, grid (125,8) ----------------
// Per-row arithmetic identical to prior rounds (64-elem f32 chunks, f64 totals).
__global__ __launch_bounds__(256) void k_z0(const float* __restrict__ x,
                                            const float* __restrict__ Wi,
                                            const float* __restrict__ bi,
                                            float* ws) {
    int col = blockIdx.x * 256 + threadIdx.x;   // 125*256 = 32000, exact
    int rg  = blockIdx.y;                       // 0..7
    int b = col / T_;
    int t = col - b * T_;
    const float* xp = x + (size_t)b * (D_ * T_) + t;
    const float* Wr = Wi + rg * 8 * D_;         // uniform base

    double tot[8];
    #pragma unroll
    for (int r = 0; r < 8; ++r) tot[r] = 0.0;

    for (int ch = 0; ch < 8; ++ch) {
        float chk[8];
        #pragma unroll
        for (int r = 0; r < 8; ++r) chk[r] = 0.0f;
        #pragma unroll
        for (int k4 = 0; k4 < 16; ++k4) {
            int d = ch * 64 + k4 * 4;
            float x0 = xp[(size_t)(d + 0) * T_];
            float x1 = xp[(size_t)(d + 1) * T_];
            float x2 = xp[(size_t)(d + 2) * T_];
            float x3 = xp[(size_t)(d + 3) * T_];
            #pragma unroll
            for (int r = 0; r < 8; ++r) {
                const float* w = Wr + r * D_ + d;   // uniform -> SGPR
                chk[r] = fmaf(w[0], x0, fmaf(w[1], x1, fmaf(w[2], x2, fmaf(w[3], x3, chk[r]))));
            }
        }
        #pragma unroll
        for (int r = 0; r < 8; ++r) tot[r] += (double)chk[r];
    }

    #pragma unroll
    for (int r = 0; r < 8; ++r) {
        int row = rg * 8 + r;        // q*8+c
        int q = row >> 3, c = row & 7;
        float bias = bi[row];
        for (int p = 0; p < q; ++p) bias -= ws[WS_VBP + (q * 8 + p) * 8 + c];
        ws[WS_Z0 + (size_t)row * NCOL + col] = (float)tot[r] + bias;
    }
}

// ---------------- K_vq: 1000 blocks, 32 cols/block, 8 scanners/col ----------------
// Wave w (full 64 lanes), lane-pair half h: scans codes [(2w+h)*128, +128) for
// column blk*32 + (lane>>1). Merge: pair via shfl_xor(1) (index-preference),
// then R3-proven LDS merge across 4 waves (ranges ascend -> strict > = first-max).
__global__ __launch_bounds__(256) void k_vq(const float* __restrict__ cb,
                                            float* ws, float* __restrict__ out) {
    __shared__ float s_val[4][32];
    __shared__ int   s_idx[4][32];

    int tid  = threadIdx.x;
    int wid  = tid >> 6;
    int lane = tid & 63;
    int ci   = lane >> 1;
    int half = lane & 1;
    int blk  = blockIdx.x;       // 0..999
    int col  = blk * 32 + ci;
    int seg  = wid * 2 + half;   // 0..7

    const float* z0 = ws + WS_Z0;
    const float* M  = ws + WS_M;

    float zqh[Q_][CD_];
    float lossv[Q_];

    #pragma unroll
    for (int q = 0; q < Q_; ++q) {
        // z_e = Z0 - corrections (computed redundantly by all 8 scanners of a col)
        float ze[CD_];
        #pragma unroll
        for (int c = 0; c < CD_; ++c) ze[c] = z0[(q * 8 + c) * NCOL + col];
        #pragma unroll
        for (int p = 0; p < q; ++p) {
            const float4* Mp = (const float4*)(M + (q * 8 + p) * 64);
            #pragma unroll
            for (int c = 0; c < CD_; ++c) {
                float4 a = Mp[c * 2 + 0];
                float4 bq = Mp[c * 2 + 1];
                float tc = a.x * zqh[p][0];
                tc = fmaf(a.y,  zqh[p][1], tc);
                tc = fmaf(a.z,  zqh[p][2], tc);
                tc = fmaf(a.w,  zqh[p][3], tc);
                tc = fmaf(bq.x, zqh[p][4], tc);
                tc = fmaf(bq.y, zqh[p][5], tc);
                tc = fmaf(bq.z, zqh[p][6], tc);
                tc = fmaf(bq.w, zqh[p][7], tc);
                ze[c] -= tc;
            }
        }

        // partial argmax over this segment's 128 codes
        const float4* cb4 = (const float4*)(cb + ((size_t)q * CS_ + seg * 128) * CD_);
        const float*  iv  = ws + WS_INV + q * CS_ + seg * 128;
        float b0 = -1e30f, b1 = -1e30f, b2 = -1e30f, b3 = -1e30f;
        int   n0 = 0, n1 = 1, n2 = 2, n3 = 3;
        for (int i = 0; i < 128; i += 4) {
            float4 a0 = cb4[(i + 0) * 2], x0 = cb4[(i + 0) * 2 + 1];
            float4 a1 = cb4[(i + 1) * 2], x1 = cb4[(i + 1) * 2 + 1];
            float4 a2 = cb4[(i + 2) * 2], x2 = cb4[(i + 2) * 2 + 1];
            float4 a3 = cb4[(i + 3) * 2], x3 = cb4[(i + 3) * 2 + 1];
            float4 iv4 = *(const float4*)(iv + i);
            float s0 = ze[0] * a0.x; s0 = fmaf(ze[1], a0.y, s0); s0 = fmaf(ze[2], a0.z, s0); s0 = fmaf(ze[3], a0.w, s0);
            s0 = fmaf(ze[4], x0.x, s0); s0 = fmaf(ze[5], x0.y, s0); s0 = fmaf(ze[6], x0.z, s0); s0 = fmaf(ze[7], x0.w, s0);
            float s1 = ze[0] * a1.x; s1 = fmaf(ze[1], a1.y, s1); s1 = fmaf(ze[2], a1.z, s1); s1 = fmaf(ze[3], a1.w, s1);
            s1 = fmaf(ze[4], x1.x, s1); s1 = fmaf(ze[5], x1.y, s1); s1 = fmaf(ze[6], x1.z, s1); s1 = fmaf(ze[7], x1.w, s1);
            float s2 = ze[0] * a2.x; s2 = fmaf(ze[1], a2.y, s2); s2 = fmaf(ze[2], a2.z, s2); s2 = fmaf(ze[3], a2.w, s2);
            s2 = fmaf(ze[4], x2.x, s2); s2 = fmaf(ze[5], x2.y, s2); s2 = fmaf(ze[6], x2.z, s2); s2 = fmaf(ze[7], x2.w, s2);
            float s3 = ze[0] * a3.x; s3 = fmaf(ze[1], a3.y, s3); s3 = fmaf(ze[2], a3.z, s3); s3 = fmaf(ze[3], a3.w, s3);
            s3 = fmaf(ze[4], x3.x, s3); s3 = fmaf(ze[5], x3.y, s3); s3 = fmaf(ze[6], x3.z, s3); s3 = fmaf(ze[7], x3.w, s3);
            s0 *= iv4.x;
            s1 *= iv4.y;
            s2 *= iv4.z;
            s3 *= iv4.w;
            if (s0 > b0) { b0 = s0; n0 = i + 0; }
            if (s1 > b1) { b1 = s1; n1 = i + 1; }
            if (s2 > b2) { b2 = s2; n2 = i + 2; }
            if (s3 > b3) { b3 = s3; n3 = i + 3; }
        }
        // merge 4 chains (tie -> lowest index)
        float bb = b0; int nn = n0;
        if (b1 > bb || (b1 == bb && n1 < nn)) { bb = b1; nn = n1; }
        if (b2 > bb || (b2 == bb && n2 < nn)) { bb = b2; nn = n2; }
        if (b3 > bb || (b3 == bb && n3 < nn)) { bb = b3; nn = n3; }
        nn += seg * 128;

        // pair merge across the two half-lanes (index preference -> first-max)
        float ob = __shfl_xor(bb, 1);
        int   on = __shfl_xor(nn, 1);
        if (ob > bb || (ob == bb && on < nn)) { bb = ob; nn = on; }

        // both lanes of the pair hold identical winner; benign same-value write
        s_val[wid][ci] = bb;
        s_idx[wid][ci] = nn;
        __syncthreads();

        // cross-wave merge (code ranges ascend with wid -> strict > keeps first-max)
        float gb = s_val[0][ci]; int gn = s_idx[0][ci];
        float t1 = s_val[1][ci]; int m1 = s_idx[1][ci];
        float t2 = s_val[2][ci]; int m2 = s_idx[2][ci];
        float t3 = s_val[3][ci]; int m3 = s_idx[3][ci];
        if (t1 > gb) { gb = t1; gn = m1; }
        if (t2 > gb) { gb = t2; gn = m2; }
        if (t3 > gb) { gb = t3; gn = m3; }
        __syncthreads();

        // gather winner code vector from global (raw codebook, L2-hot)
        const float4* zrow = (const float4*)(cb + ((size_t)q * CS_ + gn) * CD_);
        float4 za = zrow[0], zb = zrow[1];
        zqh[q][0] = za.x; zqh[q][1] = za.y; zqh[q][2] = za.z; zqh[q][3] = za.w;
        zqh[q][4] = zb.x; zqh[q][5] = zb.y; zqh[q][6] = zb.z; zqh[q][7] = zb.w;

        if (wid == 0 && half == 0) {
            out[OFF_IDX + q * NCOL + col] = (float)gn;
            float l = 0.0f;
            #pragma unroll
            for (int c = 0; c < CD_; ++c) { float dd = ze[c] - zqh[q][c]; l = fmaf(dd, dd, l); }
            lossv[q] = l;
            #pragma unroll
            for (int c = 0; c < CD_; ++c) ws[WS_ZQ + (q * 8 + c) * NCOL + col] = zqh[q][c];
        } else {
            lossv[q] = 0.0f;
        }
    }

    // per-block loss partials from wave 0 (even lanes hold values, odd lanes zero)
    if (wid == 0) {
        #pragma unroll
        for (int q = 0; q < Q_; ++q) {
            float l = lossv[q];
            l += __shfl_xor(l, 1);
            l += __shfl_xor(l, 2);
            l += __shfl_xor(l, 4);
            l += __shfl_xor(l, 8);
            l += __shfl_xor(l, 16);
            l += __shfl_xor(l, 32);
            if (lane == 0) ws[WS_LP + q * 1000 + blk] = l;
        }
    }
}

// ---------------- K_out: thread = column, 32 d-rows/block, grid (125,16) ----------------
__global__ __launch_bounds__(256) void k_out(const float* __restrict__ Wo,
                                             const float* __restrict__ bo,
                                             const float* __restrict__ ws,
                                             float* __restrict__ out) {
    int col = blockIdx.x * 256 + threadIdx.x;
    int d0  = blockIdx.y * 32;
    int b = col / T_;
    int t = col - b * T_;

    float zq[Q_][CD_];
    #pragma unroll
    for (int q = 0; q < Q_; ++q)
        #pragma unroll
        for (int c = 0; c < CD_; ++c)
            zq[q][c] = ws[WS_ZQ + (q * 8 + c) * NCOL + col];

    size_t cbase = ((size_t)b * D_) * T_ + t;
    #pragma unroll 4
    for (int dd = 0; dd < 32; ++dd) {
        int d = d0 + dd;
        float qsum = 0.0f;
        size_t dbase = cbase + (size_t)d * T_;
        #pragma unroll
        for (int q = 0; q < Q_; ++q) {
            const float* wr = Wo + (q * D_ + d) * CD_;   // uniform -> scalar loads
            float qv = bo[q * D_ + d];
            qv = fmaf(wr[0], zq[q][0], qv);
            qv = fmaf(wr[1], zq[q][1], qv);
            qv = fmaf(wr[2], zq[q][2], qv);
            qv = fmaf(wr[3], zq[q][3], qv);
            qv = fmaf(wr[4], zq[q][4], qv);
            qv = fmaf(wr[5], zq[q][5], qv);
            qv = fmaf(wr[6], zq[q][6], qv);
            qv = fmaf(wr[7], zq[q][7], qv);
            out[OFF_ALLQ + (size_t)q * (B_ * D_ * T_) + dbase] = qv;
            qsum += qv;
        }
        out[OFF_QOUT + dbase] = qsum;
    }
}

// ---------------- K_loss: finalize 8 losses from per-block partials ----------------
__global__ void k_loss(const float* __restrict__ ws, float* __restrict__ out) {
    int tid = threadIdx.x;        // 256
    int q = tid >> 5, i = tid & 31;
    double s = 0.0;
    for (int j = i; j < 1000; j += 32) s += (double)ws[WS_LP + q * 1000 + j];
    s += __shfl_xor(s, 1);
    s += __shfl_xor(s, 2);
    s += __shfl_xor(s, 4);
    s += __shfl_xor(s, 8);
    s += __shfl_xor(s, 16);
    if (i == 0) out[OFF_LOSS + q] = (float)(1.25 * s / 256000.0);
}

extern "C" void kernel_launch(void* const* d_in, const int* in_sizes, int n_in,
                              void* d_out, int out_size, void* d_ws, size_t ws_size,
                              hipStream_t stream) {
    const float* x  = (const float*)d_in[0];
    const float* Wi = (const float*)d_in[1];
    const float* bi = (const float*)d_in[2];
    const float* Wo = (const float*)d_in[3];
    const float* bo = (const float*)d_in[4];
    const float* cb = (const float*)d_in[5];
    float* out = (float*)d_out;
    float* ws  = (float*)d_ws;

    hipLaunchKernelGGL(k_pre,  dim3(96),      dim3(256), 0, stream, Wi, Wo, bo, cb, ws);
    hipLaunchKernelGGL(k_z0,   dim3(125, 8),  dim3(256), 0, stream, x, Wi, bi, ws);
    hipLaunchKernelGGL(k_vq,   dim3(1000),    dim3(256), 0, stream, cb, ws, out);
    hipLaunchKernelGGL(k_out,  dim3(125, 16), dim3(256), 0, stream, Wo, bo, ws, out);
    hipLaunchKernelGGL(k_loss, dim3(1),       dim3(256), 0, stream, ws, out);
}

// Round 8
// 737.214 us; speedup vs baseline: 1.3229x; 1.3229x over previous
//
#include <hip/hip_runtime.h>

#define B_   16
#define D_   512
#define T_   2000
#define Q_   8
#define CD_  8
#define CS_  1024
#define NCOL 32000   // B_*T_

// workspace float offsets
#define WS_Z0   0              // 64*32000 = 2048000
#define WS_ZQ   2048000        // 64*32000 = 2048000
#define WS_M    4096000        // 64*64    = 4096
#define WS_VBP  4100096        // 8*8*8    = 512
#define WS_LP   4100608        // 8*500    = 4000
#define WS_INV  4108608        // 8*1024   = 8192

// d_out float offsets (quantized_out, all_idx, all_loss, all_q)
#define OFF_QOUT 0
#define OFF_IDX  16384000
#define OFF_LOSS 16640000
#define OFF_ALLQ 16640008

// ---------------- K_pre: fused M + vbp + codebook inverse norms ----------------
__global__ __launch_bounds__(256) void k_pre(const float* __restrict__ Wi,
                                             const float* __restrict__ Wo,
                                             const float* __restrict__ bo,
                                             const float* __restrict__ cb,
                                             float* __restrict__ ws) {
    int blk = blockIdx.x, tid = threadIdx.x;
    if (blk < 64) {
        int q = blk >> 3, p = blk & 7;
        if (tid < 64) {
            int c = tid >> 3, cp = tid & 7;
            const float* wir = Wi + (q * CD_ + c) * D_;
            const float* wop = Wo + p * (D_ * CD_) + cp;
            double acc = 0.0;
            #pragma unroll 4
            for (int d = 0; d < D_; ++d) acc += (double)wir[d] * (double)wop[d * CD_];
            ws[WS_M + (q * 8 + p) * 64 + c * 8 + cp] = (float)acc;
        } else if (tid < 128) {
            int s = tid - 64;
            int c = s >> 3, ds = s & 7;
            double a = 0.0;
            if (p < q) {
                const float* wir = Wi + (q * CD_ + c) * D_;
                const float* bop = bo + p * D_;
                for (int d = ds; d < D_; d += 8) a += (double)wir[d] * (double)bop[d];
            }
            a += __shfl_xor(a, 1);
            a += __shfl_xor(a, 2);
            a += __shfl_xor(a, 4);
            if (ds == 0) ws[WS_VBP + (q * 8 + p) * 8 + c] = (float)a;
        }
    } else {
        int id = (blk - 64) * 256 + tid;   // 0..8191
        const float4* r = (const float4*)(cb + (size_t)id * CD_);
        float4 v = r[0], w = r[1];
        float ss = v.x * v.x + v.y * v.y + v.z * v.z + v.w * v.w;
        float so = w.x * w.x + w.y * w.y + w.z * w.z + w.w * w.w;
        float nrm = sqrtf(ss + so);
        ws[WS_INV + id] = 1.0f / fmaxf(nrm, 1e-12f);
    }
}

// ---------------- K_z0: Z0[row][col], 8 rows/thread, grid (125,8) ----------------
__global__ __launch_bounds__(256) void k_z0(const float* __restrict__ x,
                                            const float* __restrict__ Wi,
                                            const float* __restrict__ bi,
                                            float* ws) {
    int col = blockIdx.x * 256 + threadIdx.x;   // 125*256 = 32000, exact
    int rg  = blockIdx.y;                       // 0..7
    int b = col / T_;
    int t = col - b * T_;
    const float* xp = x + (size_t)b * (D_ * T_) + t;
    const float* Wr = Wi + rg * 8 * D_;         // uniform base

    double tot[8];
    #pragma unroll
    for (int r = 0; r < 8; ++r) tot[r] = 0.0;

    for (int ch = 0; ch < 8; ++ch) {
        float chk[8];
        #pragma unroll
        for (int r = 0; r < 8; ++r) chk[r] = 0.0f;
        #pragma unroll
        for (int k4 = 0; k4 < 16; ++k4) {
            int d = ch * 64 + k4 * 4;
            float x0 = xp[(size_t)(d + 0) * T_];
            float x1 = xp[(size_t)(d + 1) * T_];
            float x2 = xp[(size_t)(d + 2) * T_];
            float x3 = xp[(size_t)(d + 3) * T_];
            #pragma unroll
            for (int r = 0; r < 8; ++r) {
                const float* w = Wr + r * D_ + d;   // uniform -> SGPR
                chk[r] = fmaf(w[0], x0, fmaf(w[1], x1, fmaf(w[2], x2, fmaf(w[3], x3, chk[r]))));
            }
        }
        #pragma unroll
        for (int r = 0; r < 8; ++r) tot[r] += (double)chk[r];
    }

    #pragma unroll
    for (int r = 0; r < 8; ++r) {
        int row = rg * 8 + r;        // q*8+c
        int q = row >> 3, c = row & 7;
        float bias = bi[row];
        for (int p = 0; p < q; ++p) bias -= ws[WS_VBP + (q * 8 + p) * 8 + c];
        ws[WS_Z0 + (size_t)row * NCOL + col] = (float)tot[r] + bias;
    }
}

// ---------------- K_vq: 4 waves/block, SGPR codebook, LDS merge (R3/R5-proven, unmodified) ----------------
__global__ __launch_bounds__(256) void k_vq(const float* __restrict__ cb,
                                            float* ws, float* __restrict__ out) {
    __shared__ float s_val[4][64];
    __shared__ int   s_idx[4][64];

    int tid  = threadIdx.x;
    int wid  = tid >> 6;
    int lane = tid & 63;
    int blk  = blockIdx.x;
    int col  = blk * 64 + lane;

    const float* z0 = ws + WS_Z0;
    const float* M  = ws + WS_M;

    float zqh[Q_][CD_];
    float lossv[Q_];

    #pragma unroll
    for (int q = 0; q < Q_; ++q) {
        // z_e = Z0 - corrections (computed redundantly in every wave)
        float ze[CD_];
        #pragma unroll
        for (int c = 0; c < CD_; ++c) ze[c] = z0[(q * 8 + c) * NCOL + col];
        #pragma unroll
        for (int p = 0; p < q; ++p) {
            const float4* Mp = (const float4*)(M + (q * 8 + p) * 64);
            #pragma unroll
            for (int c = 0; c < CD_; ++c) {
                float4 a = Mp[c * 2 + 0];
                float4 bq = Mp[c * 2 + 1];
                float tc = a.x * zqh[p][0];
                tc = fmaf(a.y,  zqh[p][1], tc);
                tc = fmaf(a.z,  zqh[p][2], tc);
                tc = fmaf(a.w,  zqh[p][3], tc);
                tc = fmaf(bq.x, zqh[p][4], tc);
                tc = fmaf(bq.y, zqh[p][5], tc);
                tc = fmaf(bq.z, zqh[p][6], tc);
                tc = fmaf(bq.w, zqh[p][7], tc);
                ze[c] -= tc;
            }
        }

        // partial argmax over this wave's 256 codes (uniform scalar loads)
        const float4* cb4 = (const float4*)(cb + ((size_t)q * CS_ + wid * 256) * CD_);
        const float*  iv  = ws + WS_INV + q * CS_ + wid * 256;
        float b0 = -1e30f, b1 = -1e30f, b2 = -1e30f, b3 = -1e30f;
        int   n0 = 0, n1 = 1, n2 = 2, n3 = 3;
        for (int i = 0; i < 256; i += 4) {
            float4 a0 = cb4[(i + 0) * 2], x0 = cb4[(i + 0) * 2 + 1];
            float4 a1 = cb4[(i + 1) * 2], x1 = cb4[(i + 1) * 2 + 1];
            float4 a2 = cb4[(i + 2) * 2], x2 = cb4[(i + 2) * 2 + 1];
            float4 a3 = cb4[(i + 3) * 2], x3 = cb4[(i + 3) * 2 + 1];
            float4 iv4 = *(const float4*)(iv + i);
            float s0 = ze[0] * a0.x; s0 = fmaf(ze[1], a0.y, s0); s0 = fmaf(ze[2], a0.z, s0); s0 = fmaf(ze[3], a0.w, s0);
            s0 = fmaf(ze[4], x0.x, s0); s0 = fmaf(ze[5], x0.y, s0); s0 = fmaf(ze[6], x0.z, s0); s0 = fmaf(ze[7], x0.w, s0);
            float s1 = ze[0] * a1.x; s1 = fmaf(ze[1], a1.y, s1); s1 = fmaf(ze[2], a1.z, s1); s1 = fmaf(ze[3], a1.w, s1);
            s1 = fmaf(ze[4], x1.x, s1); s1 = fmaf(ze[5], x1.y, s1); s1 = fmaf(ze[6], x1.z, s1); s1 = fmaf(ze[7], x1.w, s1);
            float s2 = ze[0] * a2.x; s2 = fmaf(ze[1], a2.y, s2); s2 = fmaf(ze[2], a2.z, s2); s2 = fmaf(ze[3], a2.w, s2);
            s2 = fmaf(ze[4], x2.x, s2); s2 = fmaf(ze[5], x2.y, s2); s2 = fmaf(ze[6], x2.z, s2); s2 = fmaf(ze[7], x2.w, s2);
            float s3 = ze[0] * a3.x; s3 = fmaf(ze[1], a3.y, s3); s3 = fmaf(ze[2], a3.z, s3); s3 = fmaf(ze[3], a3.w, s3);
            s3 = fmaf(ze[4], x3.x, s3); s3 = fmaf(ze[5], x3.y, s3); s3 = fmaf(ze[6], x3.z, s3); s3 = fmaf(ze[7], x3.w, s3);
            s0 *= iv4.x;
            s1 *= iv4.y;
            s2 *= iv4.z;
            s3 *= iv4.w;
            if (s0 > b0) { b0 = s0; n0 = i + 0; }
            if (s1 > b1) { b1 = s1; n1 = i + 1; }
            if (s2 > b2) { b2 = s2; n2 = i + 2; }
            if (s3 > b3) { b3 = s3; n3 = i + 3; }
        }
        // merge 4 chains (tie -> lowest index)
        float bb = b0; int nn = n0;
        if (b1 > bb || (b1 == bb && n1 < nn)) { bb = b1; nn = n1; }
        if (b2 > bb || (b2 == bb && n2 < nn)) { bb = b2; nn = n2; }
        if (b3 > bb || (b3 == bb && n3 < nn)) { bb = b3; nn = n3; }
        nn += wid * 256;

        s_val[wid][lane] = bb;
        s_idx[wid][lane] = nn;
        __syncthreads();

        // cross-wave merge (redundant in all waves). Ranges increase with wid,
        // so strict > keeps the first-max index.
        float gb = s_val[0][lane]; int gn = s_idx[0][lane];
        float t1 = s_val[1][lane]; int m1 = s_idx[1][lane];
        float t2 = s_val[2][lane]; int m2 = s_idx[2][lane];
        float t3 = s_val[3][lane]; int m3 = s_idx[3][lane];
        if (t1 > gb) { gb = t1; gn = m1; }
        if (t2 > gb) { gb = t2; gn = m2; }
        if (t3 > gb) { gb = t3; gn = m3; }
        __syncthreads();

        // gather winner code vector from global (raw codebook)
        const float4* zrow = (const float4*)(cb + ((size_t)q * CS_ + gn) * CD_);
        float4 za = zrow[0], zb = zrow[1];
        zqh[q][0] = za.x; zqh[q][1] = za.y; zqh[q][2] = za.z; zqh[q][3] = za.w;
        zqh[q][4] = zb.x; zqh[q][5] = zb.y; zqh[q][6] = zb.z; zqh[q][7] = zb.w;

        if (wid == 0) {
            out[OFF_IDX + q * NCOL + col] = (float)gn;
            float l = 0.0f;
            #pragma unroll
            for (int c = 0; c < CD_; ++c) { float dd = ze[c] - zqh[q][c]; l = fmaf(dd, dd, l); }
            lossv[q] = l;
            #pragma unroll
            for (int c = 0; c < CD_; ++c) ws[WS_ZQ + (q * 8 + c) * NCOL + col] = zqh[q][c];
        } else {
            lossv[q] = 0.0f;
        }
    }

    // per-block loss partials from wave 0 (deterministic, no atomics)
    if (wid == 0) {
        #pragma unroll
        for (int q = 0; q < Q_; ++q) {
            float l = lossv[q];
            l += __shfl_xor(l, 1);
            l += __shfl_xor(l, 2);
            l += __shfl_xor(l, 4);
            l += __shfl_xor(l, 8);
            l += __shfl_xor(l, 16);
            l += __shfl_xor(l, 32);
            if (lane == 0) ws[WS_LP + q * 500 + blk] = l;
        }
    }
}

// ---------------- K_out: 2 cols/thread, float2 stores, grid (125,16), block 128 ----------------
// Pure per-thread kernel (no LDS/shuffles, disjoint stores). Same fmaf order as
// prior passing rounds; stores are 8B vectorized.
__global__ __launch_bounds__(128) void k_out(const float* __restrict__ Wo,
                                             const float* __restrict__ bo,
                                             const float* __restrict__ ws,
                                             float* __restrict__ out) {
    int col0 = blockIdx.x * 256 + threadIdx.x * 2;   // even; 125*256 = 32000
    int d0   = blockIdx.y * 32;
    int b = col0 / T_;                               // col0,col0+1 share b (T_ even)
    int t = col0 - b * T_;

    float zq0[Q_][CD_], zq1[Q_][CD_];
    #pragma unroll
    for (int q = 0; q < Q_; ++q)
        #pragma unroll
        for (int c = 0; c < CD_; ++c) {
            float2 v = *(const float2*)(ws + WS_ZQ + (q * 8 + c) * NCOL + col0);
            zq0[q][c] = v.x;
            zq1[q][c] = v.y;
        }

    size_t cbase = ((size_t)b * D_) * T_ + t;
    #pragma unroll 2
    for (int dd = 0; dd < 32; ++dd) {
        int d = d0 + dd;
        float qs0 = 0.0f, qs1 = 0.0f;
        size_t dbase = cbase + (size_t)d * T_;
        #pragma unroll
        for (int q = 0; q < Q_; ++q) {
            const float* wr = Wo + (q * D_ + d) * CD_;   // uniform -> scalar loads
            float qb = bo[q * D_ + d];
            float q0 = qb, q1 = qb;
            #pragma unroll
            for (int c = 0; c < CD_; ++c) {
                q0 = fmaf(wr[c], zq0[q][c], q0);
                q1 = fmaf(wr[c], zq1[q][c], q1);
            }
            *(float2*)(out + OFF_ALLQ + (size_t)q * (B_ * D_ * T_) + dbase) = make_float2(q0, q1);
            qs0 += q0;
            qs1 += q1;
        }
        *(float2*)(out + OFF_QOUT + dbase) = make_float2(qs0, qs1);
    }
}

// ---------------- K_loss: finalize 8 losses from per-block partials ----------------
__global__ void k_loss(const float* __restrict__ ws, float* __restrict__ out) {
    int tid = threadIdx.x;        // 256
    int q = tid >> 5, i = tid & 31;
    double s = 0.0;
    for (int j = i; j < 500; j += 32) s += (double)ws[WS_LP + q * 500 + j];
    s += __shfl_xor(s, 1);
    s += __shfl_xor(s, 2);
    s += __shfl_xor(s, 4);
    s += __shfl_xor(s, 8);
    s += __shfl_xor(s, 16);
    if (i == 0) out[OFF_LOSS + q] = (float)(1.25 * s / 256000.0);
}

extern "C" void kernel_launch(void* const* d_in, const int* in_sizes, int n_in,
                              void* d_out, int out_size, void* d_ws, size_t ws_size,
                              hipStream_t stream) {
    const float* x  = (const float*)d_in[0];
    const float* Wi = (const float*)d_in[1];
    const float* bi = (const float*)d_in[2];
    const float* Wo = (const float*)d_in[3];
    const float* bo = (const float*)d_in[4];
    const float* cb = (const float*)d_in[5];
    float* out = (float*)d_out;
    float* ws  = (float*)d_ws;

    hipLaunchKernelGGL(k_pre,  dim3(96),      dim3(256), 0, stream, Wi, Wo, bo, cb, ws);
    hipLaunchKernelGGL(k_z0,   dim3(125, 8),  dim3(256), 0, stream, x, Wi, bi, ws);
    hipLaunchKernelGGL(k_vq,   dim3(500),     dim3(256), 0, stream, cb, ws, out);
    hipLaunchKernelGGL(k_out,  dim3(125, 16), dim3(128), 0, stream, Wo, bo, ws, out);
    hipLaunchKernelGGL(k_loss, dim3(1),       dim3(256), 0, stream, ws, out);
}

// Round 9
// 704.542 us; speedup vs baseline: 1.3843x; 1.0464x over previous
//
#include <hip/hip_runtime.h>

#define B_   16
#define D_   512
#define T_   2000
#define Q_   8
#define CD_  8
#define CS_  1024
#define NCOL 32000   // B_*T_

// workspace float offsets
#define WS_Z0   0              // 64*32000 = 2048000
#define WS_ZQ   2048000        // 64*32000 = 2048000
#define WS_M    4096000        // 64*64    = 4096
#define WS_VBP  4100096        // 8*8*8    = 512
#define WS_LP   4100608        // 8*500    = 4000
#define WS_INV  4108608        // 8*1024   = 8192

// d_out float offsets (quantized_out, all_idx, all_loss, all_q)
#define OFF_QOUT 0
#define OFF_IDX  16384000
#define OFF_LOSS 16640000
#define OFF_ALLQ 16640008

// ---------------- K_pre: fused M + vbp + codebook inverse norms ----------------
__global__ __launch_bounds__(256) void k_pre(const float* __restrict__ Wi,
                                             const float* __restrict__ Wo,
                                             const float* __restrict__ bo,
                                             const float* __restrict__ cb,
                                             float* __restrict__ ws) {
    int blk = blockIdx.x, tid = threadIdx.x;
    if (blk < 64) {
        int q = blk >> 3, p = blk & 7;
        if (tid < 64) {
            int c = tid >> 3, cp = tid & 7;
            const float* wir = Wi + (q * CD_ + c) * D_;
            const float* wop = Wo + p * (D_ * CD_) + cp;
            double acc = 0.0;
            #pragma unroll 4
            for (int d = 0; d < D_; ++d) acc += (double)wir[d] * (double)wop[d * CD_];
            ws[WS_M + (q * 8 + p) * 64 + c * 8 + cp] = (float)acc;
        } else if (tid < 128) {
            int s = tid - 64;
            int c = s >> 3, ds = s & 7;
            double a = 0.0;
            if (p < q) {
                const float* wir = Wi + (q * CD_ + c) * D_;
                const float* bop = bo + p * D_;
                for (int d = ds; d < D_; d += 8) a += (double)wir[d] * (double)bop[d];
            }
            a += __shfl_xor(a, 1);
            a += __shfl_xor(a, 2);
            a += __shfl_xor(a, 4);
            if (ds == 0) ws[WS_VBP + (q * 8 + p) * 8 + c] = (float)a;
        }
    } else {
        int id = (blk - 64) * 256 + tid;   // 0..8191
        const float4* r = (const float4*)(cb + (size_t)id * CD_);
        float4 v = r[0], w = r[1];
        float ss = v.x * v.x + v.y * v.y + v.z * v.z + v.w * v.w;
        float so = w.x * w.x + w.y * w.y + w.z * w.z + w.w * w.w;
        float nrm = sqrtf(ss + so);
        ws[WS_INV + id] = 1.0f / fmaxf(nrm, 1e-12f);
    }
}

// ---------------- K_z0: Z0[row][col], 8 rows/thread, grid (125,8) ----------------
// Same arithmetic as R8; ws split into restrict-qualified region pointers.
__global__ __launch_bounds__(256) void k_z0(const float* __restrict__ x,
                                            const float* __restrict__ Wi,
                                            const float* __restrict__ bi,
                                            const float* __restrict__ vbp,
                                            float* __restrict__ z0o) {
    int col = blockIdx.x * 256 + threadIdx.x;   // 125*256 = 32000, exact
    int rg  = blockIdx.y;                       // 0..7
    int b = col / T_;
    int t = col - b * T_;
    const float* xp = x + (size_t)b * (D_ * T_) + t;
    const float* Wr = Wi + rg * 8 * D_;         // uniform base

    double tot[8];
    #pragma unroll
    for (int r = 0; r < 8; ++r) tot[r] = 0.0;

    for (int ch = 0; ch < 8; ++ch) {
        float chk[8];
        #pragma unroll
        for (int r = 0; r < 8; ++r) chk[r] = 0.0f;
        #pragma unroll
        for (int k4 = 0; k4 < 16; ++k4) {
            int d = ch * 64 + k4 * 4;
            float x0 = xp[(size_t)(d + 0) * T_];
            float x1 = xp[(size_t)(d + 1) * T_];
            float x2 = xp[(size_t)(d + 2) * T_];
            float x3 = xp[(size_t)(d + 3) * T_];
            #pragma unroll
            for (int r = 0; r < 8; ++r) {
                const float* w = Wr + r * D_ + d;   // uniform -> SGPR
                chk[r] = fmaf(w[0], x0, fmaf(w[1], x1, fmaf(w[2], x2, fmaf(w[3], x3, chk[r]))));
            }
        }
        #pragma unroll
        for (int r = 0; r < 8; ++r) tot[r] += (double)chk[r];
    }

    #pragma unroll
    for (int r = 0; r < 8; ++r) {
        int row = rg * 8 + r;        // q*8+c
        int q = row >> 3, c = row & 7;
        float bias = bi[row];
        for (int p = 0; p < q; ++p) bias -= vbp[(q * 8 + p) * 8 + c];
        z0o[(size_t)row * NCOL + col] = (float)tot[r] + bias;
    }
}

// ---------------- K_vq: 4 waves/block, LDS merge (R3/R5/R8-proven topology) ----------------
// Only changes vs R8: ws split into restrict region pointers; unroll 2 on scan.
__global__ __launch_bounds__(256) void k_vq(const float* __restrict__ cb,
                                            const float* __restrict__ z0,
                                            const float* __restrict__ M,
                                            const float* __restrict__ inv,
                                            float* __restrict__ zqo,
                                            float* __restrict__ lp,
                                            float* __restrict__ out) {
    __shared__ float s_val[4][64];
    __shared__ int   s_idx[4][64];

    int tid  = threadIdx.x;
    int wid  = tid >> 6;
    int lane = tid & 63;
    int blk  = blockIdx.x;
    int col  = blk * 64 + lane;

    float zqh[Q_][CD_];
    float lossv[Q_];

    #pragma unroll
    for (int q = 0; q < Q_; ++q) {
        // z_e = Z0 - corrections (computed redundantly in every wave)
        float ze[CD_];
        #pragma unroll
        for (int c = 0; c < CD_; ++c) ze[c] = z0[(q * 8 + c) * NCOL + col];
        #pragma unroll
        for (int p = 0; p < q; ++p) {
            const float4* Mp = (const float4*)(M + (q * 8 + p) * 64);
            #pragma unroll
            for (int c = 0; c < CD_; ++c) {
                float4 a = Mp[c * 2 + 0];
                float4 bq = Mp[c * 2 + 1];
                float tc = a.x * zqh[p][0];
                tc = fmaf(a.y,  zqh[p][1], tc);
                tc = fmaf(a.z,  zqh[p][2], tc);
                tc = fmaf(a.w,  zqh[p][3], tc);
                tc = fmaf(bq.x, zqh[p][4], tc);
                tc = fmaf(bq.y, zqh[p][5], tc);
                tc = fmaf(bq.z, zqh[p][6], tc);
                tc = fmaf(bq.w, zqh[p][7], tc);
                ze[c] -= tc;
            }
        }

        // partial argmax over this wave's 256 codes (wave-uniform addresses)
        const float4* cb4 = (const float4*)(cb + ((size_t)q * CS_ + wid * 256) * CD_);
        const float*  iv  = inv + q * CS_ + wid * 256;
        float b0 = -1e30f, b1 = -1e30f, b2 = -1e30f, b3 = -1e30f;
        int   n0 = 0, n1 = 1, n2 = 2, n3 = 3;
        #pragma unroll 2
        for (int i = 0; i < 256; i += 4) {
            float4 a0 = cb4[(i + 0) * 2], x0 = cb4[(i + 0) * 2 + 1];
            float4 a1 = cb4[(i + 1) * 2], x1 = cb4[(i + 1) * 2 + 1];
            float4 a2 = cb4[(i + 2) * 2], x2 = cb4[(i + 2) * 2 + 1];
            float4 a3 = cb4[(i + 3) * 2], x3 = cb4[(i + 3) * 2 + 1];
            float4 iv4 = *(const float4*)(iv + i);
            float s0 = ze[0] * a0.x; s0 = fmaf(ze[1], a0.y, s0); s0 = fmaf(ze[2], a0.z, s0); s0 = fmaf(ze[3], a0.w, s0);
            s0 = fmaf(ze[4], x0.x, s0); s0 = fmaf(ze[5], x0.y, s0); s0 = fmaf(ze[6], x0.z, s0); s0 = fmaf(ze[7], x0.w, s0);
            float s1 = ze[0] * a1.x; s1 = fmaf(ze[1], a1.y, s1); s1 = fmaf(ze[2], a1.z, s1); s1 = fmaf(ze[3], a1.w, s1);
            s1 = fmaf(ze[4], x1.x, s1); s1 = fmaf(ze[5], x1.y, s1); s1 = fmaf(ze[6], x1.z, s1); s1 = fmaf(ze[7], x1.w, s1);
            float s2 = ze[0] * a2.x; s2 = fmaf(ze[1], a2.y, s2); s2 = fmaf(ze[2], a2.z, s2); s2 = fmaf(ze[3], a2.w, s2);
            s2 = fmaf(ze[4], x2.x, s2); s2 = fmaf(ze[5], x2.y, s2); s2 = fmaf(ze[6], x2.z, s2); s2 = fmaf(ze[7], x2.w, s2);
            float s3 = ze[0] * a3.x; s3 = fmaf(ze[1], a3.y, s3); s3 = fmaf(ze[2], a3.z, s3); s3 = fmaf(ze[3], a3.w, s3);
            s3 = fmaf(ze[4], x3.x, s3); s3 = fmaf(ze[5], x3.y, s3); s3 = fmaf(ze[6], x3.z, s3); s3 = fmaf(ze[7], x3.w, s3);
            s0 *= iv4.x;
            s1 *= iv4.y;
            s2 *= iv4.z;
            s3 *= iv4.w;
            if (s0 > b0) { b0 = s0; n0 = i + 0; }
            if (s1 > b1) { b1 = s1; n1 = i + 1; }
            if (s2 > b2) { b2 = s2; n2 = i + 2; }
            if (s3 > b3) { b3 = s3; n3 = i + 3; }
        }
        // merge 4 chains (tie -> lowest index)
        float bb = b0; int nn = n0;
        if (b1 > bb || (b1 == bb && n1 < nn)) { bb = b1; nn = n1; }
        if (b2 > bb || (b2 == bb && n2 < nn)) { bb = b2; nn = n2; }
        if (b3 > bb || (b3 == bb && n3 < nn)) { bb = b3; nn = n3; }
        nn += wid * 256;

        s_val[wid][lane] = bb;
        s_idx[wid][lane] = nn;
        __syncthreads();

        // cross-wave merge (ranges ascend with wid; strict > keeps first-max)
        float gb = s_val[0][lane]; int gn = s_idx[0][lane];
        float t1 = s_val[1][lane]; int m1 = s_idx[1][lane];
        float t2 = s_val[2][lane]; int m2 = s_idx[2][lane];
        float t3 = s_val[3][lane]; int m3 = s_idx[3][lane];
        if (t1 > gb) { gb = t1; gn = m1; }
        if (t2 > gb) { gb = t2; gn = m2; }
        if (t3 > gb) { gb = t3; gn = m3; }
        __syncthreads();

        // gather winner code vector from global (raw codebook)
        const float4* zrow = (const float4*)(cb + ((size_t)q * CS_ + gn) * CD_);
        float4 za = zrow[0], zb = zrow[1];
        zqh[q][0] = za.x; zqh[q][1] = za.y; zqh[q][2] = za.z; zqh[q][3] = za.w;
        zqh[q][4] = zb.x; zqh[q][5] = zb.y; zqh[q][6] = zb.z; zqh[q][7] = zb.w;

        if (wid == 0) {
            out[OFF_IDX + q * NCOL + col] = (float)gn;
            float l = 0.0f;
            #pragma unroll
            for (int c = 0; c < CD_; ++c) { float dd = ze[c] - zqh[q][c]; l = fmaf(dd, dd, l); }
            lossv[q] = l;
            #pragma unroll
            for (int c = 0; c < CD_; ++c) zqo[(q * 8 + c) * NCOL + col] = zqh[q][c];
        } else {
            lossv[q] = 0.0f;
        }
    }

    // per-block loss partials from wave 0 (deterministic, no atomics)
    if (wid == 0) {
        #pragma unroll
        for (int q = 0; q < Q_; ++q) {
            float l = lossv[q];
            l += __shfl_xor(l, 1);
            l += __shfl_xor(l, 2);
            l += __shfl_xor(l, 4);
            l += __shfl_xor(l, 8);
            l += __shfl_xor(l, 16);
            l += __shfl_xor(l, 32);
            if (lane == 0) lp[q * 500 + blk] = l;
        }
    }
}

// ---------------- K_out: 2 cols/thread, float2 stores, 16 d-rows/block, grid (125,32) ----------------
__global__ __launch_bounds__(128) void k_out(const float* __restrict__ Wo,
                                             const float* __restrict__ bo,
                                             const float* __restrict__ ws,
                                             float* __restrict__ out) {
    int col0 = blockIdx.x * 256 + threadIdx.x * 2;   // even; 125*256 = 32000
    int d0   = blockIdx.y * 16;
    int b = col0 / T_;                               // col0,col0+1 share b (T_ even)
    int t = col0 - b * T_;

    float zq0[Q_][CD_], zq1[Q_][CD_];
    #pragma unroll
    for (int q = 0; q < Q_; ++q)
        #pragma unroll
        for (int c = 0; c < CD_; ++c) {
            float2 v = *(const float2*)(ws + WS_ZQ + (q * 8 + c) * NCOL + col0);
            zq0[q][c] = v.x;
            zq1[q][c] = v.y;
        }

    size_t cbase = ((size_t)b * D_) * T_ + t;
    #pragma unroll 2
    for (int dd = 0; dd < 16; ++dd) {
        int d = d0 + dd;
        float qs0 = 0.0f, qs1 = 0.0f;
        size_t dbase = cbase + (size_t)d * T_;
        #pragma unroll
        for (int q = 0; q < Q_; ++q) {
            const float* wr = Wo + (q * D_ + d) * CD_;   // uniform -> scalar loads
            float qb = bo[q * D_ + d];
            float q0 = qb, q1 = qb;
            #pragma unroll
            for (int c = 0; c < CD_; ++c) {
                q0 = fmaf(wr[c], zq0[q][c], q0);
                q1 = fmaf(wr[c], zq1[q][c], q1);
            }
            *(float2*)(out + OFF_ALLQ + (size_t)q * (B_ * D_ * T_) + dbase) = make_float2(q0, q1);
            qs0 += q0;
            qs1 += q1;
        }
        *(float2*)(out + OFF_QOUT + dbase) = make_float2(qs0, qs1);
    }
}

// ---------------- K_loss: finalize 8 losses from per-block partials ----------------
__global__ void k_loss(const float* __restrict__ ws, float* __restrict__ out) {
    int tid = threadIdx.x;        // 256
    int q = tid >> 5, i = tid & 31;
    double s = 0.0;
    for (int j = i; j < 500; j += 32) s += (double)ws[WS_LP + q * 500 + j];
    s += __shfl_xor(s, 1);
    s += __shfl_xor(s, 2);
    s += __shfl_xor(s, 4);
    s += __shfl_xor(s, 8);
    s += __shfl_xor(s, 16);
    if (i == 0) out[OFF_LOSS + q] = (float)(1.25 * s / 256000.0);
}

extern "C" void kernel_launch(void* const* d_in, const int* in_sizes, int n_in,
                              void* d_out, int out_size, void* d_ws, size_t ws_size,
                              hipStream_t stream) {
    const float* x  = (const float*)d_in[0];
    const float* Wi = (const float*)d_in[1];
    const float* bi = (const float*)d_in[2];
    const float* Wo = (const float*)d_in[3];
    const float* bo = (const float*)d_in[4];
    const float* cb = (const float*)d_in[5];
    float* out = (float*)d_out;
    float* ws  = (float*)d_ws;

    hipLaunchKernelGGL(k_pre,  dim3(96),      dim3(256), 0, stream, Wi, Wo, bo, cb, ws);
    hipLaunchKernelGGL(k_z0,   dim3(125, 8),  dim3(256), 0, stream, x, Wi, bi,
                       ws + WS_VBP, ws + WS_Z0);
    hipLaunchKernelGGL(k_vq,   dim3(500),     dim3(256), 0, stream, cb,
                       ws + WS_Z0, ws + WS_M, ws + WS_INV, ws + WS_ZQ, ws + WS_LP, out);
    hipLaunchKernelGGL(k_out,  dim3(125, 32), dim3(128), 0, stream, Wo, bo, ws, out);
    hipLaunchKernelGGL(k_loss, dim3(1),       dim3(256), 0, stream, ws, out);
}

// Round 10
// 619.803 us; speedup vs baseline: 1.5735x; 1.1367x over previous
//
#include <hip/hip_runtime.h>

#define B_   16
#define D_   512
#define T_   2000
#define Q_   8
#define CD_  8
#define CS_  1024
#define NCOL 32000   // B_*T_

// workspace float offsets
#define WS_Z0   0              // 64*32000 = 2048000
#define WS_ZQ   2048000        // 64*32000 = 2048000
#define WS_M    4096000        // 64*64    = 4096
#define WS_VBP  4100096        // 8*8*8    = 512
#define WS_LP   4100608        // 8*500    = 4000
#define WS_INV  4108608        // 8*1024   = 8192

// d_out float offsets (quantized_out, all_idx, all_loss, all_q)
#define OFF_QOUT 0
#define OFF_IDX  16384000
#define OFF_LOSS 16640000
#define OFF_ALLQ 16640008

// ---------------- K_pre: fused M + vbp + codebook inverse norms ----------------
__global__ __launch_bounds__(256) void k_pre(const float* __restrict__ Wi,
                                             const float* __restrict__ Wo,
                                             const float* __restrict__ bo,
                                             const float* __restrict__ cb,
                                             float* __restrict__ ws) {
    int blk = blockIdx.x, tid = threadIdx.x;
    if (blk < 64) {
        int q = blk >> 3, p = blk & 7;
        if (tid < 64) {
            int c = tid >> 3, cp = tid & 7;
            const float* wir = Wi + (q * CD_ + c) * D_;
            const float* wop = Wo + p * (D_ * CD_) + cp;
            double acc = 0.0;
            #pragma unroll 4
            for (int d = 0; d < D_; ++d) acc += (double)wir[d] * (double)wop[d * CD_];
            ws[WS_M + (q * 8 + p) * 64 + c * 8 + cp] = (float)acc;
        } else if (tid < 128) {
            int s = tid - 64;
            int c = s >> 3, ds = s & 7;
            double a = 0.0;
            if (p < q) {
                const float* wir = Wi + (q * CD_ + c) * D_;
                const float* bop = bo + p * D_;
                for (int d = ds; d < D_; d += 8) a += (double)wir[d] * (double)bop[d];
            }
            a += __shfl_xor(a, 1);
            a += __shfl_xor(a, 2);
            a += __shfl_xor(a, 4);
            if (ds == 0) ws[WS_VBP + (q * 8 + p) * 8 + c] = (float)a;
        }
    } else {
        int id = (blk - 64) * 256 + tid;   // 0..8191
        const float4* r = (const float4*)(cb + (size_t)id * CD_);
        float4 v = r[0], w = r[1];
        float ss = v.x * v.x + v.y * v.y + v.z * v.z + v.w * v.w;
        float so = w.x * w.x + w.y * w.y + w.z * w.z + w.w * w.w;
        float nrm = sqrtf(ss + so);
        ws[WS_INV + id] = 1.0f / fmaxf(nrm, 1e-12f);
    }
}

// ---------------- K_z0: Z0[row][col], 8 rows/thread, grid (125,8) ----------------
__global__ __launch_bounds__(256) void k_z0(const float* __restrict__ x,
                                            const float* __restrict__ Wi,
                                            const float* __restrict__ bi,
                                            const float* __restrict__ vbp,
                                            float* __restrict__ z0o) {
    int col = blockIdx.x * 256 + threadIdx.x;   // 125*256 = 32000, exact
    int rg  = blockIdx.y;                       // 0..7
    int b = col / T_;
    int t = col - b * T_;
    const float* xp = x + (size_t)b * (D_ * T_) + t;
    const float* Wr = Wi + rg * 8 * D_;         // uniform base (blockIdx only -> s_load)

    double tot[8];
    #pragma unroll
    for (int r = 0; r < 8; ++r) tot[r] = 0.0;

    for (int ch = 0; ch < 8; ++ch) {
        float chk[8];
        #pragma unroll
        for (int r = 0; r < 8; ++r) chk[r] = 0.0f;
        #pragma unroll
        for (int k4 = 0; k4 < 16; ++k4) {
            int d = ch * 64 + k4 * 4;
            float x0 = xp[(size_t)(d + 0) * T_];
            float x1 = xp[(size_t)(d + 1) * T_];
            float x2 = xp[(size_t)(d + 2) * T_];
            float x3 = xp[(size_t)(d + 3) * T_];
            #pragma unroll
            for (int r = 0; r < 8; ++r) {
                const float* w = Wr + r * D_ + d;   // uniform -> SGPR
                chk[r] = fmaf(w[0], x0, fmaf(w[1], x1, fmaf(w[2], x2, fmaf(w[3], x3, chk[r]))));
            }
        }
        #pragma unroll
        for (int r = 0; r < 8; ++r) tot[r] += (double)chk[r];
    }

    #pragma unroll
    for (int r = 0; r < 8; ++r) {
        int row = rg * 8 + r;        // q*8+c
        int q = row >> 3, c = row & 7;
        float bias = bi[row];
        for (int p = 0; p < q; ++p) bias -= vbp[(q * 8 + p) * 8 + c];
        z0o[(size_t)row * NCOL + col] = (float)tot[r] + bias;
    }
}

// ---------------- K_vq: 4 waves/block, LDS merge (proven topology) ----------------
// Change vs R9: wid-derived segment offset goes through readfirstlane so the
// compiler can PROVE wave-uniformity -> codebook/invnorm loads become s_load
// (scalar cache) instead of per-lane broadcast global_load.
__global__ __launch_bounds__(256) void k_vq(const float* __restrict__ cb,
                                            const float* __restrict__ z0,
                                            const float* __restrict__ M,
                                            const float* __restrict__ inv,
                                            float* __restrict__ zqo,
                                            float* __restrict__ lp,
                                            float* __restrict__ out) {
    __shared__ float s_val[4][64];
    __shared__ int   s_idx[4][64];

    int tid  = threadIdx.x;
    int wid  = tid >> 6;
    int lane = tid & 63;
    int blk  = blockIdx.x;
    int col  = blk * 64 + lane;

    // exact: all lanes of a wave share wid; makes segoff provably SGPR
    int segoff = __builtin_amdgcn_readfirstlane(wid * 256);

    float zqh[Q_][CD_];
    float lossv[Q_];

    #pragma unroll
    for (int q = 0; q < Q_; ++q) {
        // z_e = Z0 - corrections (computed redundantly in every wave)
        float ze[CD_];
        #pragma unroll
        for (int c = 0; c < CD_; ++c) ze[c] = z0[(q * 8 + c) * NCOL + col];
        #pragma unroll
        for (int p = 0; p < q; ++p) {
            const float4* Mp = (const float4*)(M + (q * 8 + p) * 64);
            #pragma unroll
            for (int c = 0; c < CD_; ++c) {
                float4 a = Mp[c * 2 + 0];
                float4 bq = Mp[c * 2 + 1];
                float tc = a.x * zqh[p][0];
                tc = fmaf(a.y,  zqh[p][1], tc);
                tc = fmaf(a.z,  zqh[p][2], tc);
                tc = fmaf(a.w,  zqh[p][3], tc);
                tc = fmaf(bq.x, zqh[p][4], tc);
                tc = fmaf(bq.y, zqh[p][5], tc);
                tc = fmaf(bq.z, zqh[p][6], tc);
                tc = fmaf(bq.w, zqh[p][7], tc);
                ze[c] -= tc;
            }
        }

        // partial argmax over this wave's 256 codes (scalar-cache loads)
        const float4* cb4 = (const float4*)(cb + ((size_t)q * CS_ + segoff) * CD_);
        const float*  iv  = inv + q * CS_ + segoff;
        float b0 = -1e30f, b1 = -1e30f, b2 = -1e30f, b3 = -1e30f;
        int   n0 = 0, n1 = 1, n2 = 2, n3 = 3;
        #pragma unroll 2
        for (int i = 0; i < 256; i += 4) {
            float4 a0 = cb4[(i + 0) * 2], x0 = cb4[(i + 0) * 2 + 1];
            float4 a1 = cb4[(i + 1) * 2], x1 = cb4[(i + 1) * 2 + 1];
            float4 a2 = cb4[(i + 2) * 2], x2 = cb4[(i + 2) * 2 + 1];
            float4 a3 = cb4[(i + 3) * 2], x3 = cb4[(i + 3) * 2 + 1];
            float4 iv4 = *(const float4*)(iv + i);
            float s0 = ze[0] * a0.x; s0 = fmaf(ze[1], a0.y, s0); s0 = fmaf(ze[2], a0.z, s0); s0 = fmaf(ze[3], a0.w, s0);
            s0 = fmaf(ze[4], x0.x, s0); s0 = fmaf(ze[5], x0.y, s0); s0 = fmaf(ze[6], x0.z, s0); s0 = fmaf(ze[7], x0.w, s0);
            float s1 = ze[0] * a1.x; s1 = fmaf(ze[1], a1.y, s1); s1 = fmaf(ze[2], a1.z, s1); s1 = fmaf(ze[3], a1.w, s1);
            s1 = fmaf(ze[4], x1.x, s1); s1 = fmaf(ze[5], x1.y, s1); s1 = fmaf(ze[6], x1.z, s1); s1 = fmaf(ze[7], x1.w, s1);
            float s2 = ze[0] * a2.x; s2 = fmaf(ze[1], a2.y, s2); s2 = fmaf(ze[2], a2.z, s2); s2 = fmaf(ze[3], a2.w, s2);
            s2 = fmaf(ze[4], x2.x, s2); s2 = fmaf(ze[5], x2.y, s2); s2 = fmaf(ze[6], x2.z, s2); s2 = fmaf(ze[7], x2.w, s2);
            float s3 = ze[0] * a3.x; s3 = fmaf(ze[1], a3.y, s3); s3 = fmaf(ze[2], a3.z, s3); s3 = fmaf(ze[3], a3.w, s3);
            s3 = fmaf(ze[4], x3.x, s3); s3 = fmaf(ze[5], x3.y, s3); s3 = fmaf(ze[6], x3.z, s3); s3 = fmaf(ze[7], x3.w, s3);
            s0 *= iv4.x;
            s1 *= iv4.y;
            s2 *= iv4.z;
            s3 *= iv4.w;
            if (s0 > b0) { b0 = s0; n0 = i + 0; }
            if (s1 > b1) { b1 = s1; n1 = i + 1; }
            if (s2 > b2) { b2 = s2; n2 = i + 2; }
            if (s3 > b3) { b3 = s3; n3 = i + 3; }
        }
        // merge 4 chains (tie -> lowest index)
        float bb = b0; int nn = n0;
        if (b1 > bb || (b1 == bb && n1 < nn)) { bb = b1; nn = n1; }
        if (b2 > bb || (b2 == bb && n2 < nn)) { bb = b2; nn = n2; }
        if (b3 > bb || (b3 == bb && n3 < nn)) { bb = b3; nn = n3; }
        nn += segoff;

        s_val[wid][lane] = bb;
        s_idx[wid][lane] = nn;
        __syncthreads();

        // cross-wave merge (ranges ascend with wid; strict > keeps first-max)
        float gb = s_val[0][lane]; int gn = s_idx[0][lane];
        float t1 = s_val[1][lane]; int m1 = s_idx[1][lane];
        float t2 = s_val[2][lane]; int m2 = s_idx[2][lane];
        float t3 = s_val[3][lane]; int m3 = s_idx[3][lane];
        if (t1 > gb) { gb = t1; gn = m1; }
        if (t2 > gb) { gb = t2; gn = m2; }
        if (t3 > gb) { gb = t3; gn = m3; }
        __syncthreads();

        // gather winner code vector from global (raw codebook, per-lane index)
        const float4* zrow = (const float4*)(cb + ((size_t)q * CS_ + gn) * CD_);
        float4 za = zrow[0], zb = zrow[1];
        zqh[q][0] = za.x; zqh[q][1] = za.y; zqh[q][2] = za.z; zqh[q][3] = za.w;
        zqh[q][4] = zb.x; zqh[q][5] = zb.y; zqh[q][6] = zb.z; zqh[q][7] = zb.w;

        if (wid == 0) {
            out[OFF_IDX + q * NCOL + col] = (float)gn;
            float l = 0.0f;
            #pragma unroll
            for (int c = 0; c < CD_; ++c) { float dd = ze[c] - zqh[q][c]; l = fmaf(dd, dd, l); }
            lossv[q] = l;
            #pragma unroll
            for (int c = 0; c < CD_; ++c) zqo[(q * 8 + c) * NCOL + col] = zqh[q][c];
        } else {
            lossv[q] = 0.0f;
        }
    }

    // per-block loss partials from wave 0 (deterministic, no atomics)
    if (wid == 0) {
        #pragma unroll
        for (int q = 0; q < Q_; ++q) {
            float l = lossv[q];
            l += __shfl_xor(l, 1);
            l += __shfl_xor(l, 2);
            l += __shfl_xor(l, 4);
            l += __shfl_xor(l, 8);
            l += __shfl_xor(l, 16);
            l += __shfl_xor(l, 32);
            if (lane == 0) lp[q * 500 + blk] = l;
        }
    }
}

// ---------------- K_out: 2 cols/thread, float2 stores, 16 d-rows/block, grid (125,32) ----------------
__global__ __launch_bounds__(128) void k_out(const float* __restrict__ Wo,
                                             const float* __restrict__ bo,
                                             const float* __restrict__ ws,
                                             float* __restrict__ out) {
    int col0 = blockIdx.x * 256 + threadIdx.x * 2;   // even; 125*256 = 32000
    int d0   = blockIdx.y * 16;
    int b = col0 / T_;                               // col0,col0+1 share b (T_ even)
    int t = col0 - b * T_;

    float zq0[Q_][CD_], zq1[Q_][CD_];
    #pragma unroll
    for (int q = 0; q < Q_; ++q)
        #pragma unroll
        for (int c = 0; c < CD_; ++c) {
            float2 v = *(const float2*)(ws + WS_ZQ + (q * 8 + c) * NCOL + col0);
            zq0[q][c] = v.x;
            zq1[q][c] = v.y;
        }

    size_t cbase = ((size_t)b * D_) * T_ + t;
    #pragma unroll 2
    for (int dd = 0; dd < 16; ++dd) {
        int d = d0 + dd;
        float qs0 = 0.0f, qs1 = 0.0f;
        size_t dbase = cbase + (size_t)d * T_;
        #pragma unroll
        for (int q = 0; q < Q_; ++q) {
            const float* wr = Wo + (q * D_ + d) * CD_;   // uniform -> scalar loads
            float qb = bo[q * D_ + d];
            float q0 = qb, q1 = qb;
            #pragma unroll
            for (int c = 0; c < CD_; ++c) {
                q0 = fmaf(wr[c], zq0[q][c], q0);
                q1 = fmaf(wr[c], zq1[q][c], q1);
            }
            *(float2*)(out + OFF_ALLQ + (size_t)q * (B_ * D_ * T_) + dbase) = make_float2(q0, q1);
            qs0 += q0;
            qs1 += q1;
        }
        *(float2*)(out + OFF_QOUT + dbase) = make_float2(qs0, qs1);
    }
}

// ---------------- K_loss: finalize 8 losses from per-block partials ----------------
__global__ void k_loss(const float* __restrict__ ws, float* __restrict__ out) {
    int tid = threadIdx.x;        // 256
    int q = tid >> 5, i = tid & 31;
    double s = 0.0;
    for (int j = i; j < 500; j += 32) s += (double)ws[WS_LP + q * 500 + j];
    s += __shfl_xor(s, 1);
    s += __shfl_xor(s, 2);
    s += __shfl_xor(s, 4);
    s += __shfl_xor(s, 8);
    s += __shfl_xor(s, 16);
    if (i == 0) out[OFF_LOSS + q] = (float)(1.25 * s / 256000.0);
}

extern "C" void kernel_launch(void* const* d_in, const int* in_sizes, int n_in,
                              void* d_out, int out_size, void* d_ws, size_t ws_size,
                              hipStream_t stream) {
    const float* x  = (const float*)d_in[0];
    const float* Wi = (const float*)d_in[1];
    const float* bi = (const float*)d_in[2];
    const float* Wo = (const float*)d_in[3];
    const float* bo = (const float*)d_in[4];
    const float* cb = (const float*)d_in[5];
    float* out = (float*)d_out;
    float* ws  = (float*)d_ws;

    hipLaunchKernelGGL(k_pre,  dim3(96),      dim3(256), 0, stream, Wi, Wo, bo, cb, ws);
    hipLaunchKernelGGL(k_z0,   dim3(125, 8),  dim3(256), 0, stream, x, Wi, bi,
                       ws + WS_VBP, ws + WS_Z0);
    hipLaunchKernelGGL(k_vq,   dim3(500),     dim3(256), 0, stream, cb,
                       ws + WS_Z0, ws + WS_M, ws + WS_INV, ws + WS_ZQ, ws + WS_LP, out);
    hipLaunchKernelGGL(k_out,  dim3(125, 32), dim3(128), 0, stream, Wo, bo, ws, out);
    hipLaunchKernelGGL(k_loss, dim3(1),       dim3(256), 0, stream, ws, out);
}

// Round 11
// 515.340 us; speedup vs baseline: 1.8925x; 1.2027x over previous
//
#include <hip/hip_runtime.h>

#define B_   16
#define D_   512
#define T_   2000
#define Q_   8
#define CD_  8
#define CS_  1024
#define NCOL 32000   // B_*T_

// workspace float offsets
#define WS_Z0   0              // 64*32000 = 2048000
#define WS_ZQ   2048000        // 64*32000 = 2048000
#define WS_M    4096000        // 64*64    = 4096
#define WS_VBP  4100096        // 8*8*8    = 512
#define WS_LP   4100608        // 8*500    = 4000
#define WS_INV  4108608        // 8*1024   = 8192

// d_out float offsets (quantized_out, all_idx, all_loss, all_q)
#define OFF_QOUT 0
#define OFF_IDX  16384000
#define OFF_LOSS 16640000
#define OFF_ALLQ 16640008

// ---------------- K_pre: fused M + vbp + codebook inverse norms ----------------
__global__ __launch_bounds__(256) void k_pre(const float* __restrict__ Wi,
                                             const float* __restrict__ Wo,
                                             const float* __restrict__ bo,
                                             const float* __restrict__ cb,
                                             float* __restrict__ ws) {
    int blk = blockIdx.x, tid = threadIdx.x;
    if (blk < 64) {
        int q = blk >> 3, p = blk & 7;
        if (tid < 64) {
            int c = tid >> 3, cp = tid & 7;
            const float* wir = Wi + (q * CD_ + c) * D_;
            const float* wop = Wo + p * (D_ * CD_) + cp;
            double acc = 0.0;
            #pragma unroll 4
            for (int d = 0; d < D_; ++d) acc += (double)wir[d] * (double)wop[d * CD_];
            ws[WS_M + (q * 8 + p) * 64 + c * 8 + cp] = (float)acc;
        } else if (tid < 128) {
            int s = tid - 64;
            int c = s >> 3, ds = s & 7;
            double a = 0.0;
            if (p < q) {
                const float* wir = Wi + (q * CD_ + c) * D_;
                const float* bop = bo + p * D_;
                for (int d = ds; d < D_; d += 8) a += (double)wir[d] * (double)bop[d];
            }
            a += __shfl_xor(a, 1);
            a += __shfl_xor(a, 2);
            a += __shfl_xor(a, 4);
            if (ds == 0) ws[WS_VBP + (q * 8 + p) * 8 + c] = (float)a;
        }
    } else {
        int id = (blk - 64) * 256 + tid;   // 0..8191
        const float4* r = (const float4*)(cb + (size_t)id * CD_);
        float4 v = r[0], w = r[1];
        float ss = v.x * v.x + v.y * v.y + v.z * v.z + v.w * v.w;
        float so = w.x * w.x + w.y * w.y + w.z * w.z + w.w * w.w;
        float nrm = sqrtf(ss + so);
        ws[WS_INV + id] = 1.0f / fmaxf(nrm, 1e-12f);
    }
}

// ---------------- K_z0: Z0[row][col], 8 rows/thread, grid (125,8) ----------------
__global__ __launch_bounds__(256) void k_z0(const float* __restrict__ x,
                                            const float* __restrict__ Wi,
                                            const float* __restrict__ bi,
                                            const float* __restrict__ vbp,
                                            float* __restrict__ z0o) {
    int col = blockIdx.x * 256 + threadIdx.x;   // 125*256 = 32000, exact
    int rg  = blockIdx.y;                       // 0..7
    int b = col / T_;
    int t = col - b * T_;
    const float* xp = x + (size_t)b * (D_ * T_) + t;
    const float* Wr = Wi + rg * 8 * D_;         // uniform base (blockIdx only -> s_load)

    double tot[8];
    #pragma unroll
    for (int r = 0; r < 8; ++r) tot[r] = 0.0;

    for (int ch = 0; ch < 8; ++ch) {
        float chk[8];
        #pragma unroll
        for (int r = 0; r < 8; ++r) chk[r] = 0.0f;
        #pragma unroll
        for (int k4 = 0; k4 < 16; ++k4) {
            int d = ch * 64 + k4 * 4;
            float x0 = xp[(size_t)(d + 0) * T_];
            float x1 = xp[(size_t)(d + 1) * T_];
            float x2 = xp[(size_t)(d + 2) * T_];
            float x3 = xp[(size_t)(d + 3) * T_];
            #pragma unroll
            for (int r = 0; r < 8; ++r) {
                const float* w = Wr + r * D_ + d;   // uniform -> SGPR
                chk[r] = fmaf(w[0], x0, fmaf(w[1], x1, fmaf(w[2], x2, fmaf(w[3], x3, chk[r]))));
            }
        }
        #pragma unroll
        for (int r = 0; r < 8; ++r) tot[r] += (double)chk[r];
    }

    #pragma unroll
    for (int r = 0; r < 8; ++r) {
        int row = rg * 8 + r;        // q*8+c
        int q = row >> 3, c = row & 7;
        float bias = bi[row];
        for (int p = 0; p < q; ++p) bias -= vbp[(q * 8 + p) * 8 + c];
        z0o[(size_t)row * NCOL + col] = (float)tot[r] + bias;
    }
}

// ---------------- K_vq: 4 waves/block, LDS merge (proven topology; R10 + unroll 4) ----------------
__global__ __launch_bounds__(256) void k_vq(const float* __restrict__ cb,
                                            const float* __restrict__ z0,
                                            const float* __restrict__ M,
                                            const float* __restrict__ inv,
                                            float* __restrict__ zqo,
                                            float* __restrict__ lp,
                                            float* __restrict__ out) {
    __shared__ float s_val[4][64];
    __shared__ int   s_idx[4][64];

    int tid  = threadIdx.x;
    int wid  = tid >> 6;
    int lane = tid & 63;
    int blk  = blockIdx.x;
    int col  = blk * 64 + lane;

    // exact: all lanes of a wave share wid; makes segoff provably SGPR
    int segoff = __builtin_amdgcn_readfirstlane(wid * 256);

    float zqh[Q_][CD_];
    float lossv[Q_];

    #pragma unroll
    for (int q = 0; q < Q_; ++q) {
        // z_e = Z0 - corrections (computed redundantly in every wave)
        float ze[CD_];
        #pragma unroll
        for (int c = 0; c < CD_; ++c) ze[c] = z0[(q * 8 + c) * NCOL + col];
        #pragma unroll
        for (int p = 0; p < q; ++p) {
            const float4* Mp = (const float4*)(M + (q * 8 + p) * 64);
            #pragma unroll
            for (int c = 0; c < CD_; ++c) {
                float4 a = Mp[c * 2 + 0];
                float4 bq = Mp[c * 2 + 1];
                float tc = a.x * zqh[p][0];
                tc = fmaf(a.y,  zqh[p][1], tc);
                tc = fmaf(a.z,  zqh[p][2], tc);
                tc = fmaf(a.w,  zqh[p][3], tc);
                tc = fmaf(bq.x, zqh[p][4], tc);
                tc = fmaf(bq.y, zqh[p][5], tc);
                tc = fmaf(bq.z, zqh[p][6], tc);
                tc = fmaf(bq.w, zqh[p][7], tc);
                ze[c] -= tc;
            }
        }

        // partial argmax over this wave's 256 codes (scalar-cache loads)
        const float4* cb4 = (const float4*)(cb + ((size_t)q * CS_ + segoff) * CD_);
        const float*  iv  = inv + q * CS_ + segoff;
        float b0 = -1e30f, b1 = -1e30f, b2 = -1e30f, b3 = -1e30f;
        int   n0 = 0, n1 = 1, n2 = 2, n3 = 3;
        #pragma unroll 4
        for (int i = 0; i < 256; i += 4) {
            float4 a0 = cb4[(i + 0) * 2], x0 = cb4[(i + 0) * 2 + 1];
            float4 a1 = cb4[(i + 1) * 2], x1 = cb4[(i + 1) * 2 + 1];
            float4 a2 = cb4[(i + 2) * 2], x2 = cb4[(i + 2) * 2 + 1];
            float4 a3 = cb4[(i + 3) * 2], x3 = cb4[(i + 3) * 2 + 1];
            float4 iv4 = *(const float4*)(iv + i);
            float s0 = ze[0] * a0.x; s0 = fmaf(ze[1], a0.y, s0); s0 = fmaf(ze[2], a0.z, s0); s0 = fmaf(ze[3], a0.w, s0);
            s0 = fmaf(ze[4], x0.x, s0); s0 = fmaf(ze[5], x0.y, s0); s0 = fmaf(ze[6], x0.z, s0); s0 = fmaf(ze[7], x0.w, s0);
            float s1 = ze[0] * a1.x; s1 = fmaf(ze[1], a1.y, s1); s1 = fmaf(ze[2], a1.z, s1); s1 = fmaf(ze[3], a1.w, s1);
            s1 = fmaf(ze[4], x1.x, s1); s1 = fmaf(ze[5], x1.y, s1); s1 = fmaf(ze[6], x1.z, s1); s1 = fmaf(ze[7], x1.w, s1);
            float s2 = ze[0] * a2.x; s2 = fmaf(ze[1], a2.y, s2); s2 = fmaf(ze[2], a2.z, s2); s2 = fmaf(ze[3], a2.w, s2);
            s2 = fmaf(ze[4], x2.x, s2); s2 = fmaf(ze[5], x2.y, s2); s2 = fmaf(ze[6], x2.z, s2); s2 = fmaf(ze[7], x2.w, s2);
            float s3 = ze[0] * a3.x; s3 = fmaf(ze[1], a3.y, s3); s3 = fmaf(ze[2], a3.z, s3); s3 = fmaf(ze[3], a3.w, s3);
            s3 = fmaf(ze[4], x3.x, s3); s3 = fmaf(ze[5], x3.y, s3); s3 = fmaf(ze[6], x3.z, s3); s3 = fmaf(ze[7], x3.w, s3);
            s0 *= iv4.x;
            s1 *= iv4.y;
            s2 *= iv4.z;
            s3 *= iv4.w;
            if (s0 > b0) { b0 = s0; n0 = i + 0; }
            if (s1 > b1) { b1 = s1; n1 = i + 1; }
            if (s2 > b2) { b2 = s2; n2 = i + 2; }
            if (s3 > b3) { b3 = s3; n3 = i + 3; }
        }
        // merge 4 chains (tie -> lowest index)
        float bb = b0; int nn = n0;
        if (b1 > bb || (b1 == bb && n1 < nn)) { bb = b1; nn = n1; }
        if (b2 > bb || (b2 == bb && n2 < nn)) { bb = b2; nn = n2; }
        if (b3 > bb || (b3 == bb && n3 < nn)) { bb = b3; nn = n3; }
        nn += segoff;

        s_val[wid][lane] = bb;
        s_idx[wid][lane] = nn;
        __syncthreads();

        // cross-wave merge (ranges ascend with wid; strict > keeps first-max)
        float gb = s_val[0][lane]; int gn = s_idx[0][lane];
        float t1 = s_val[1][lane]; int m1 = s_idx[1][lane];
        float t2 = s_val[2][lane]; int m2 = s_idx[2][lane];
        float t3 = s_val[3][lane]; int m3 = s_idx[3][lane];
        if (t1 > gb) { gb = t1; gn = m1; }
        if (t2 > gb) { gb = t2; gn = m2; }
        if (t3 > gb) { gb = t3; gn = m3; }
        __syncthreads();

        // gather winner code vector from global (raw codebook, per-lane index)
        const float4* zrow = (const float4*)(cb + ((size_t)q * CS_ + gn) * CD_);
        float4 za = zrow[0], zb = zrow[1];
        zqh[q][0] = za.x; zqh[q][1] = za.y; zqh[q][2] = za.z; zqh[q][3] = za.w;
        zqh[q][4] = zb.x; zqh[q][5] = zb.y; zqh[q][6] = zb.z; zqh[q][7] = zb.w;

        if (wid == 0) {
            out[OFF_IDX + q * NCOL + col] = (float)gn;
            float l = 0.0f;
            #pragma unroll
            for (int c = 0; c < CD_; ++c) { float dd = ze[c] - zqh[q][c]; l = fmaf(dd, dd, l); }
            lossv[q] = l;
            #pragma unroll
            for (int c = 0; c < CD_; ++c) zqo[(q * 8 + c) * NCOL + col] = zqh[q][c];
        } else {
            lossv[q] = 0.0f;
        }
    }

    // per-block loss partials from wave 0 (deterministic, no atomics)
    if (wid == 0) {
        #pragma unroll
        for (int q = 0; q < Q_; ++q) {
            float l = lossv[q];
            l += __shfl_xor(l, 1);
            l += __shfl_xor(l, 2);
            l += __shfl_xor(l, 4);
            l += __shfl_xor(l, 8);
            l += __shfl_xor(l, 16);
            l += __shfl_xor(l, 32);
            if (lane == 0) lp[q * 500 + blk] = l;
        }
    }
}

// ---------------- K_out: q-outer, low-VGPR, float2 stores, grid (125,32), block 128 ----------------
// Per q: load zq[2][8] (16 regs), write all_q rows; qsum[2][16] accumulated in
// registers across q (same q-ascending add order as before -> bit-identical).
__global__ __launch_bounds__(128) void k_out(const float* __restrict__ Wo,
                                             const float* __restrict__ bo,
                                             const float* __restrict__ zqw,
                                             float* __restrict__ out) {
    int col0 = blockIdx.x * 256 + threadIdx.x * 2;   // even; 125*256 = 32000
    int d0   = blockIdx.y * 16;
    int b = col0 / T_;                               // col0,col0+1 share b (T_ even)
    int t = col0 - b * T_;

    float qs0[16], qs1[16];
    #pragma unroll
    for (int dd = 0; dd < 16; ++dd) { qs0[dd] = 0.0f; qs1[dd] = 0.0f; }

    size_t cbase = ((size_t)b * D_) * T_ + t;

    #pragma unroll
    for (int q = 0; q < Q_; ++q) {
        float zq0[CD_], zq1[CD_];
        #pragma unroll
        for (int c = 0; c < CD_; ++c) {
            float2 v = *(const float2*)(zqw + (q * 8 + c) * NCOL + col0);
            zq0[c] = v.x;
            zq1[c] = v.y;
        }
        size_t qbase = (size_t)q * (B_ * D_ * T_) + cbase;
        #pragma unroll 4
        for (int dd = 0; dd < 16; ++dd) {
            int d = d0 + dd;
            const float* wr = Wo + (q * D_ + d) * CD_;   // uniform -> scalar loads
            float qb = bo[q * D_ + d];
            float q0 = qb, q1 = qb;
            #pragma unroll
            for (int c = 0; c < CD_; ++c) {
                q0 = fmaf(wr[c], zq0[c], q0);
                q1 = fmaf(wr[c], zq1[c], q1);
            }
            *(float2*)(out + OFF_ALLQ + qbase + (size_t)d * T_) = make_float2(q0, q1);
            qs0[dd] += q0;
            qs1[dd] += q1;
        }
    }

    #pragma unroll
    for (int dd = 0; dd < 16; ++dd) {
        size_t dbase = cbase + (size_t)(d0 + dd) * T_;
        *(float2*)(out + OFF_QOUT + dbase) = make_float2(qs0[dd], qs1[dd]);
    }
}

// ---------------- K_loss: finalize 8 losses from per-block partials ----------------
__global__ void k_loss(const float* __restrict__ ws, float* __restrict__ out) {
    int tid = threadIdx.x;        // 256
    int q = tid >> 5, i = tid & 31;
    double s = 0.0;
    for (int j = i; j < 500; j += 32) s += (double)ws[WS_LP + q * 500 + j];
    s += __shfl_xor(s, 1);
    s += __shfl_xor(s, 2);
    s += __shfl_xor(s, 4);
    s += __shfl_xor(s, 8);
    s += __shfl_xor(s, 16);
    if (i == 0) out[OFF_LOSS + q] = (float)(1.25 * s / 256000.0);
}

extern "C" void kernel_launch(void* const* d_in, const int* in_sizes, int n_in,
                              void* d_out, int out_size, void* d_ws, size_t ws_size,
                              hipStream_t stream) {
    const float* x  = (const float*)d_in[0];
    const float* Wi = (const float*)d_in[1];
    const float* bi = (const float*)d_in[2];
    const float* Wo = (const float*)d_in[3];
    const float* bo = (const float*)d_in[4];
    const float* cb = (const float*)d_in[5];
    float* out = (float*)d_out;
    float* ws  = (float*)d_ws;

    hipLaunchKernelGGL(k_pre,  dim3(96),      dim3(256), 0, stream, Wi, Wo, bo, cb, ws);
    hipLaunchKernelGGL(k_z0,   dim3(125, 8),  dim3(256), 0, stream, x, Wi, bi,
                       ws + WS_VBP, ws + WS_Z0);
    hipLaunchKernelGGL(k_vq,   dim3(500),     dim3(256), 0, stream, cb,
                       ws + WS_Z0, ws + WS_M, ws + WS_INV, ws + WS_ZQ, ws + WS_LP, out);
    hipLaunchKernelGGL(k_out,  dim3(125, 32), dim3(128), 0, stream, Wo, bo, ws + WS_ZQ, out);
    hipLaunchKernelGGL(k_loss, dim3(1),       dim3(256), 0, stream, ws, out);
}